// Round 2
// baseline (831.354 us; speedup 1.0000x reference)
//
#include <hip/hip_runtime.h>
#include <math.h>

#define NHEAD 4
#define SEQ 1024
#define BATCH 32
#define NTOK (BATCH * SEQ)
#define NSLOT 64

// ---------------- prep: fold norms into weights, transpose, l2-normalize addresses ----------------
__global__ __launch_bounds__(256) void prep_kernel(
    const float* __restrict__ maddr, const float* __restrict__ wq,
    const float* __restrict__ wk, const float* __restrict__ wv,
    const float* __restrict__ aw, const float* __restrict__ mw,
    const float* __restrict__ mq, const float* __restrict__ fw,
    const float* __restrict__ w1, const float* __restrict__ w2,
    float* __restrict__ wqc, float* __restrict__ wkc, float* __restrict__ wvc,
    float* __restrict__ mqT, float* __restrict__ addrNT,
    float* __restrict__ w1c, float* __restrict__ w2T) {
  int tid = threadIdx.x;
  for (int i = tid; i < 4096; i += 256) {
    float s = aw[i & 63];
    wqc[i] = wq[i] * s; wkc[i] = wk[i] * s; wvc[i] = wv[i] * s;
  }
  for (int i = tid; i < 2048; i += 256) {          // mqT[e*32+a] = mem_q[a][e]*mw[e]
    int e = i >> 5, a = i & 31;
    mqT[i] = mq[a * 64 + e] * mw[e];
  }
  for (int i = tid; i < 16384; i += 256) w1c[i] = w1[i] * fw[i & 63];
  for (int i = tid; i < 16384; i += 256) {         // w2T[j*64+e] = w2[e][j]
    int j = i >> 6, e = i & 63;
    w2T[i] = w2[e * 256 + j];
  }
  if (tid < 64) {                                   // addrNT[a*64+n] = l2norm rows, transposed
    int n = tid;
    float ss = 0.f;
    for (int a = 0; a < 32; ++a) { float t = maddr[n * 32 + a]; ss += t * t; }
    float inv = 1.0f / fmaxf(sqrtf(ss), 1e-12f);
    for (int a = 0; a < 32; ++a) addrNT[a * 64 + n] = maddr[n * 32 + a] * inv;
  }
}

// ---------------- qkv: rmsnorm (folded) + 3 projections; 4 threads per token ----------------
__global__ __launch_bounds__(256) void qkv_kernel(
    const float* __restrict__ x, const float* __restrict__ wqc,
    const float* __restrict__ wkc, const float* __restrict__ wvc,
    float* __restrict__ qb, float* __restrict__ kb, float* __restrict__ vb) {
  int tid = threadIdx.x;
  int token = blockIdx.x * 64 + (tid & 63);
  int p = __builtin_amdgcn_readfirstlane(tid >> 6);
  const float4* xr4 = (const float4*)(x + (size_t)token * 64);
  float xr[64];
#pragma unroll
  for (int c = 0; c < 16; ++c) {
    float4 t = xr4[c];
    xr[4 * c] = t.x; xr[4 * c + 1] = t.y; xr[4 * c + 2] = t.z; xr[4 * c + 3] = t.w;
  }
  float s0 = 0, s1 = 0, s2 = 0, s3 = 0;
#pragma unroll
  for (int c = 0; c < 16; ++c) {
    s0 = fmaf(xr[4 * c], xr[4 * c], s0);
    s1 = fmaf(xr[4 * c + 1], xr[4 * c + 1], s1);
    s2 = fmaf(xr[4 * c + 2], xr[4 * c + 2], s2);
    s3 = fmaf(xr[4 * c + 3], xr[4 * c + 3], s3);
  }
  float rs = rsqrtf(((s0 + s1) + (s2 + s3)) * (1.0f / 64.0f) + 1e-5f);
  for (int o = 0; o < 48; ++o) {
    int idx = p * 48 + o;
    int mat = idx >> 6, r = idx & 63;
    const float4* w4 = (const float4*)((mat == 0 ? wqc : (mat == 1 ? wkc : wvc)) + r * 64);
    float a0 = 0, a1 = 0, a2 = 0, a3 = 0;
#pragma unroll
    for (int c = 0; c < 16; ++c) {
      float4 w = w4[c];
      a0 = fmaf(xr[4 * c], w.x, a0);
      a1 = fmaf(xr[4 * c + 1], w.y, a1);
      a2 = fmaf(xr[4 * c + 2], w.z, a2);
      a3 = fmaf(xr[4 * c + 3], w.w, a3);
    }
    float res = ((a0 + a1) + (a2 + a3)) * rs;
    float* dst = (mat == 0 ? qb : (mat == 1 ? kb : vb));
    dst[(size_t)token * 64 + r] = res;
  }
}

// ---------------- attention: 1 thread/query, scalar-cached K/V, online softmax ----------------
__global__ __launch_bounds__(256) void attn_kernel(
    const float* qb, const float* __restrict__ kb,
    const float* __restrict__ vb, float* avb) {
  int tid = threadIdx.x;
  int qt = blockIdx.x, h = blockIdx.y, b = blockIdx.z;
  int qi = qt * 256 + tid;
  size_t base = (size_t)b * SEQ * 64 + h * 16;
  float qv[16];
  {
    const float4* qr = (const float4*)(qb + base + (size_t)qi * 64);
#pragma unroll
    for (int c = 0; c < 4; ++c) {
      float4 t = qr[c];
      qv[4 * c] = t.x; qv[4 * c + 1] = t.y; qv[4 * c + 2] = t.z; qv[4 * c + 3] = t.w;
    }
  }
  int qmax = __builtin_amdgcn_readfirstlane(qi) + 63;  // lane0's qi + 63 = wave max (qmax+1 % 64 == 0)
  float m = -1e30f, l = 0.f;
  float o[16];
#pragma unroll
  for (int d = 0; d < 16; ++d) o[d] = 0.f;
  for (int j0 = 0; j0 <= qmax; j0 += 8) {
    float sv[8];
#pragma unroll
    for (int u = 0; u < 8; ++u) {
      int j = j0 + u;
      const float4* kr = (const float4*)(kb + base + (size_t)j * 64);
      float a0 = 0, a1 = 0, a2 = 0, a3 = 0;
#pragma unroll
      for (int c = 0; c < 4; ++c) {
        float4 kk = kr[c];
        a0 = fmaf(qv[4 * c], kk.x, a0);
        a1 = fmaf(qv[4 * c + 1], kk.y, a1);
        a2 = fmaf(qv[4 * c + 2], kk.z, a2);
        a3 = fmaf(qv[4 * c + 3], kk.w, a3);
      }
      float sc = ((a0 + a1) + (a2 + a3)) * 0.25f;
      sv[u] = (j <= qi) ? sc : -1e30f;
    }
    float gm = sv[0];
#pragma unroll
    for (int u = 1; u < 8; ++u) gm = fmaxf(gm, sv[u]);
    if (__any(gm > m)) {   // deferred rescale, amortized over 8 keys
      float mn = fmaxf(m, gm);
      float cor = __expf(m - mn);
      l *= cor;
#pragma unroll
      for (int d = 0; d < 16; ++d) o[d] *= cor;
      m = mn;
    }
#pragma unroll
    for (int u = 0; u < 8; ++u) {
      float pu = __expf(sv[u] - m);   // masked: exp(-1e30 - m) -> 0
      l += pu;
      const float4* vr = (const float4*)(vb + base + (size_t)(j0 + u) * 64);
#pragma unroll
      for (int c = 0; c < 4; ++c) {
        float4 vvv = vr[c];
        o[4 * c]     = fmaf(pu, vvv.x, o[4 * c]);
        o[4 * c + 1] = fmaf(pu, vvv.y, o[4 * c + 1]);
        o[4 * c + 2] = fmaf(pu, vvv.z, o[4 * c + 2]);
        o[4 * c + 3] = fmaf(pu, vvv.w, o[4 * c + 3]);
      }
    }
  }
  float inv = 1.0f / l;
  float4* outp = (float4*)(avb + base + (size_t)qi * 64);
#pragma unroll
  for (int c = 0; c < 4; ++c) {
    float4 t;
    t.x = o[4 * c] * inv; t.y = o[4 * c + 1] * inv;
    t.z = o[4 * c + 2] * inv; t.w = o[4 * c + 3] * inv;
    outp[c] = t;
  }
}

// ---------------- wo projection + residual + memory-read stage ----------------
__global__ __launch_bounds__(128) void womem_kernel(
    const float* __restrict__ x, const float* __restrict__ avb,
    const float* __restrict__ wo, const float* __restrict__ mqT,
    const float* __restrict__ addrNT, const float* __restrict__ mv,
    const float* __restrict__ mo, float* __restrict__ x2b) {
  __shared__ float x1s[128 * 65];
  int tid = threadIdx.x;
  int token = blockIdx.x * 128 + tid;
  int b = token >> 10;
  float av[64];
  {
    const float4* a4 = (const float4*)(avb + (size_t)token * 64);
#pragma unroll
    for (int c = 0; c < 16; ++c) {
      float4 t = a4[c];
      av[4 * c] = t.x; av[4 * c + 1] = t.y; av[4 * c + 2] = t.z; av[4 * c + 3] = t.w;
    }
  }
  const float* xr = x + (size_t)token * 64;
  for (int e = 0; e < 64; ++e) {   // x1 = x + av @ wo^T  (row e of wo is contiguous, uniform)
    const float4* wr = (const float4*)(wo + e * 64);
    float a0 = 0, a1 = 0, a2 = 0, a3 = 0;
#pragma unroll
    for (int c = 0; c < 16; ++c) {
      float4 w = wr[c];
      a0 = fmaf(av[4 * c], w.x, a0);
      a1 = fmaf(av[4 * c + 1], w.y, a1);
      a2 = fmaf(av[4 * c + 2], w.z, a2);
      a3 = fmaf(av[4 * c + 3], w.w, a3);
    }
    x1s[tid * 65 + e] = xr[e] + ((a0 + a1) + (a2 + a3));
  }
  // queries (rmsnorm rs cancels in l2norm; mem_norm folded into mqT)
  float q[32];
#pragma unroll
  for (int a = 0; a < 32; ++a) q[a] = 0.f;
  for (int e = 0; e < 64; ++e) {
    float t = x1s[tid * 65 + e];
    const float4* mr = (const float4*)(mqT + e * 32);
#pragma unroll
    for (int c = 0; c < 8; ++c) {
      float4 mm = mr[c];
      q[4 * c]     = fmaf(t, mm.x, q[4 * c]);
      q[4 * c + 1] = fmaf(t, mm.y, q[4 * c + 1]);
      q[4 * c + 2] = fmaf(t, mm.z, q[4 * c + 2]);
      q[4 * c + 3] = fmaf(t, mm.w, q[4 * c + 3]);
    }
  }
  float qq = 0.f;
#pragma unroll
  for (int a = 0; a < 32; ++a) qq = fmaf(q[a], q[a], qq);
  float sinv = 4.0f / fmaxf(sqrtf(qq), 1e-12f);   // l2norm * (1/TEMP)
  float s[64];
#pragma unroll
  for (int n = 0; n < 64; ++n) s[n] = 0.f;
#pragma unroll
  for (int a = 0; a < 32; ++a) {
    float qa = q[a];
    const float4* adr = (const float4*)(addrNT + a * 64);
#pragma unroll
    for (int c = 0; c < 16; ++c) {
      float4 an = adr[c];
      s[4 * c]     = fmaf(qa, an.x, s[4 * c]);
      s[4 * c + 1] = fmaf(qa, an.y, s[4 * c + 1]);
      s[4 * c + 2] = fmaf(qa, an.z, s[4 * c + 2]);
      s[4 * c + 3] = fmaf(qa, an.w, s[4 * c + 3]);
    }
  }
#pragma unroll
  for (int n = 0; n < 64; ++n) s[n] *= sinv;
  // top-8 (strict > keeps first index on ties, matching lax.top_k)
  float vals[8]; int idxs[8];
#pragma unroll
  for (int kk = 0; kk < 8; ++kk) {
    float bv = -1e30f; int bi = 0;
#pragma unroll
    for (int n = 0; n < 64; ++n) { if (s[n] > bv) { bv = s[n]; bi = n; } }
    vals[kk] = bv; idxs[kk] = bi;
#pragma unroll
    for (int n = 0; n < 64; ++n) s[n] = (n == bi) ? -3e30f : s[n];
  }
  float pw[8]; float psum = 0.f;
#pragma unroll
  for (int kk = 0; kk < 8; ++kk) { pw[kk] = __expf(vals[kk] - vals[0]); psum += pw[kk]; }
  float isum = 1.0f / psum;
  float rv[64];
#pragma unroll
  for (int e = 0; e < 64; ++e) rv[e] = 0.f;
#pragma unroll
  for (int kk = 0; kk < 8; ++kk) {
    float wgt = pw[kk] * isum;
    const float4* mr = (const float4*)(mv + ((size_t)(b * NSLOT + idxs[kk])) * 64);
#pragma unroll
    for (int c = 0; c < 16; ++c) {
      float4 f = mr[c];
      rv[4 * c]     = fmaf(wgt, f.x, rv[4 * c]);
      rv[4 * c + 1] = fmaf(wgt, f.y, rv[4 * c + 1]);
      rv[4 * c + 2] = fmaf(wgt, f.z, rv[4 * c + 2]);
      rv[4 * c + 3] = fmaf(wgt, f.w, rv[4 * c + 3]);
    }
  }
  for (int e = 0; e < 64; ++e) {   // x2 = x1 + rv @ mem_out^T
    const float4* mr = (const float4*)(mo + e * 64);
    float a0 = 0, a1 = 0, a2 = 0, a3 = 0;
#pragma unroll
    for (int c = 0; c < 16; ++c) {
      float4 w = mr[c];
      a0 = fmaf(rv[4 * c], w.x, a0);
      a1 = fmaf(rv[4 * c + 1], w.y, a1);
      a2 = fmaf(rv[4 * c + 2], w.z, a2);
      a3 = fmaf(rv[4 * c + 3], w.w, a3);
    }
    x2b[(size_t)token * 64 + e] = x1s[tid * 65 + e] + ((a0 + a1) + (a2 + a3));
  }
}

// ---------------- FFN: 4 threads/token over HID, LDS atomic reduce ----------------
__global__ __launch_bounds__(256) void ffn_kernel(
    const float* __restrict__ x2b, const float* __restrict__ w1c,
    const float* __restrict__ b1, const float* __restrict__ w2T,
    const float* __restrict__ b2, float* __restrict__ out) {
  __shared__ float acc[64 * 65];
  int tid = threadIdx.x;
  int tok = blockIdx.x * 64 + (tid & 63);
  int p = __builtin_amdgcn_readfirstlane(tid >> 6);
  for (int i = tid; i < 64 * 65; i += 256) acc[i] = 0.f;
  __syncthreads();
  float xr[64];
  {
    const float4* x4 = (const float4*)(x2b + (size_t)tok * 64);
#pragma unroll
    for (int c = 0; c < 16; ++c) {
      float4 t = x4[c];
      xr[4 * c] = t.x; xr[4 * c + 1] = t.y; xr[4 * c + 2] = t.z; xr[4 * c + 3] = t.w;
    }
  }
  float s0 = 0, s1 = 0, s2 = 0, s3 = 0;
#pragma unroll
  for (int c = 0; c < 16; ++c) {
    s0 = fmaf(xr[4 * c], xr[4 * c], s0);
    s1 = fmaf(xr[4 * c + 1], xr[4 * c + 1], s1);
    s2 = fmaf(xr[4 * c + 2], xr[4 * c + 2], s2);
    s3 = fmaf(xr[4 * c + 3], xr[4 * c + 3], s3);
  }
  float rs = rsqrtf(((s0 + s1) + (s2 + s3)) * (1.0f / 64.0f) + 1e-5f);
  float part[64];
#pragma unroll
  for (int e = 0; e < 64; ++e) part[e] = 0.f;
  for (int jo = 0; jo < 64; ++jo) {
    int j = p * 64 + jo;
    const float4* w1r = (const float4*)(w1c + j * 64);
    float a0 = 0, a1 = 0, a2 = 0, a3 = 0;
#pragma unroll
    for (int c = 0; c < 16; ++c) {
      float4 w = w1r[c];
      a0 = fmaf(xr[4 * c], w.x, a0);
      a1 = fmaf(xr[4 * c + 1], w.y, a1);
      a2 = fmaf(xr[4 * c + 2], w.z, a2);
      a3 = fmaf(xr[4 * c + 3], w.w, a3);
    }
    float hv = ((a0 + a1) + (a2 + a3)) * rs + b1[j];
    float g = 0.5f * hv * (1.0f + erff(hv * 0.70710678118654752f));   // exact gelu
    const float4* w2r = (const float4*)(w2T + j * 64);
#pragma unroll
    for (int c = 0; c < 16; ++c) {
      float4 w = w2r[c];
      part[4 * c]     = fmaf(g, w.x, part[4 * c]);
      part[4 * c + 1] = fmaf(g, w.y, part[4 * c + 1]);
      part[4 * c + 2] = fmaf(g, w.z, part[4 * c + 2]);
      part[4 * c + 3] = fmaf(g, w.w, part[4 * c + 3]);
    }
  }
  int lrow = tid & 63;
#pragma unroll
  for (int e = 0; e < 64; ++e) atomicAdd(&acc[lrow * 65 + e], part[e]);  // (lane+e)%32 banks: conflict-free
  __syncthreads();
  int e0 = p * 16;
#pragma unroll
  for (int i = 0; i < 16; ++i) {
    int e = e0 + i;
    out[(size_t)tok * 64 + e] = x2b[(size_t)tok * 64 + e] + b2[e] + acc[lrow * 65 + e];
  }
}

extern "C" void kernel_launch(void* const* d_in, const int* in_sizes, int n_in,
                              void* d_out, int out_size, void* d_ws, size_t ws_size,
                              hipStream_t stream) {
  const float* x    = (const float*)d_in[0];
  const float* addr = (const float*)d_in[1];
  const float* mv   = (const float*)d_in[2];
  const float* aw   = (const float*)d_in[3];
  const float* wq   = (const float*)d_in[4];
  const float* wk   = (const float*)d_in[5];
  const float* wv   = (const float*)d_in[6];
  const float* wo   = (const float*)d_in[7];
  const float* mw   = (const float*)d_in[8];
  const float* mq   = (const float*)d_in[9];
  const float* mo   = (const float*)d_in[10];
  const float* fw   = (const float*)d_in[11];
  const float* w1   = (const float*)d_in[12];
  const float* b1   = (const float*)d_in[13];
  const float* w2   = (const float*)d_in[14];
  const float* b2   = (const float*)d_in[15];

  float* ws = (float*)d_ws;
  const size_t BIG = (size_t)NTOK * 64;
  float* qb = ws;
  float* kb = ws + BIG;
  float* vb = ws + 2 * BIG;
  float* avb = qb;   // attention writes av over its own q slice (same block/thread)
  float* x2b = vb;   // v is dead after attention
  float* sm = ws + 3 * BIG;
  float* wqc = sm;            // 4096
  float* wkc = sm + 4096;     // 4096
  float* wvc = sm + 8192;     // 4096
  float* mqT = sm + 12288;    // 2048
  float* addrNT = sm + 14336; // 2048
  float* w1c = sm + 16384;    // 16384
  float* w2T = sm + 32768;    // 16384

  prep_kernel<<<1, 256, 0, stream>>>(addr, wq, wk, wv, aw, mw, mq, fw, w1, w2,
                                     wqc, wkc, wvc, mqT, addrNT, w1c, w2T);
  qkv_kernel<<<512, 256, 0, stream>>>(x, wqc, wkc, wvc, qb, kb, vb);
  attn_kernel<<<dim3(4, NHEAD, BATCH), 256, 0, stream>>>(qb, kb, vb, avb);
  womem_kernel<<<256, 128, 0, stream>>>(x, avb, wo, mqT, addrNT, mv, mo, x2b);
  ffn_kernel<<<512, 256, 0, stream>>>(x2b, w1c, b1, w2T, b2, (float*)d_out);
}

// Round 9
// 508.143 us; speedup vs baseline: 1.6361x; 1.6361x over previous
//
#include <hip/hip_runtime.h>
#include <hip/hip_bf16.h>
#include <math.h>

#define SEQ 1024
#define BATCH 32
#define NTOK (BATCH * SEQ)

// ================= prep: fold norms into weights, transpose, l2-normalize addresses =================
__global__ __launch_bounds__(256) void prep_kernel(
    const float* __restrict__ maddr, const float* __restrict__ wq,
    const float* __restrict__ wk, const float* __restrict__ wv,
    const float* __restrict__ aw, const float* __restrict__ mw,
    const float* __restrict__ mq, const float* __restrict__ fw,
    const float* __restrict__ w1, const float* __restrict__ w2,
    float* __restrict__ wall, float* __restrict__ mqT, float* __restrict__ addrNT,
    float* __restrict__ w1c, float* __restrict__ w2T) {
  int gt = blockIdx.x * 256 + threadIdx.x;
  const int GS = 64 * 256;
  for (int i = gt; i < 4096; i += GS) {
    float s = aw[i & 63];
    wall[i] = wq[i] * s;            // wqc
    wall[4096 + i] = wk[i] * s;     // wkc
    wall[8192 + i] = wv[i] * s;     // wvc
  }
  for (int i = gt; i < 2048; i += GS) {           // mqT[e*32+a] = mem_q[a][e]*mw[e]
    int e = i >> 5, a = i & 31;
    mqT[i] = mq[a * 64 + e] * mw[e];
  }
  for (int i = gt; i < 16384; i += GS) w1c[i] = w1[i] * fw[i & 63];
  for (int i = gt; i < 16384; i += GS) {          // w2T[j*64+e] = w2[e][j]
    int j = i >> 6, e = i & 63;
    w2T[i] = w2[e * 256 + j];
  }
  if (gt < 64) {                                  // addrNT[a*64+n], rows l2-normalized
    int n = gt;
    float ss = 0.f;
    for (int a = 0; a < 32; ++a) { float t = maddr[n * 32 + a]; ss += t * t; }
    float inv = 1.0f / fmaxf(sqrtf(ss), 1e-12f);
    for (int a = 0; a < 32; ++a) addrNT[a * 64 + n] = maddr[n * 32 + a] * inv;
  }
}

// ================= qkv: rmsnorm folded + 3 projections; weights in LDS =================
__global__ __launch_bounds__(256) void qkv_kernel(
    const float* __restrict__ x, const float* __restrict__ wall,
    float* __restrict__ qkvAll) {   // qb|kb|vb contiguous
  __shared__ float w[12288];        // 48 KB
  int tid = threadIdx.x;
  for (int i = tid; i < 12288; i += 256) w[i] = wall[i];
  __syncthreads();
  int token = blockIdx.x * 64 + (tid & 63);
  int p = tid >> 6;
  const float4* xr4 = (const float4*)(x + (size_t)token * 64);
  float xr[64];
#pragma unroll
  for (int c = 0; c < 16; ++c) {
    float4 t = xr4[c];
    xr[4 * c] = t.x; xr[4 * c + 1] = t.y; xr[4 * c + 2] = t.z; xr[4 * c + 3] = t.w;
  }
  float s0 = 0, s1 = 0, s2 = 0, s3 = 0;
#pragma unroll
  for (int c = 0; c < 16; ++c) {
    s0 = fmaf(xr[4 * c], xr[4 * c], s0);
    s1 = fmaf(xr[4 * c + 1], xr[4 * c + 1], s1);
    s2 = fmaf(xr[4 * c + 2], xr[4 * c + 2], s2);
    s3 = fmaf(xr[4 * c + 3], xr[4 * c + 3], s3);
  }
  float rs = rsqrtf(((s0 + s1) + (s2 + s3)) * (1.0f / 64.0f) + 1e-5f);
  const size_t BIG = (size_t)NTOK * 64;
  for (int o = 0; o < 48; ++o) {
    int idx = p * 48 + o;            // 0..191 over the 3 matrices
    const float4* w4 = (const float4*)(w + idx * 64);
    float a0 = 0, a1 = 0, a2 = 0, a3 = 0;
#pragma unroll
    for (int c = 0; c < 16; ++c) {
      float4 ww = w4[c];
      a0 = fmaf(xr[4 * c], ww.x, a0);
      a1 = fmaf(xr[4 * c + 1], ww.y, a1);
      a2 = fmaf(xr[4 * c + 2], ww.z, a2);
      a3 = fmaf(xr[4 * c + 3], ww.w, a3);
    }
    qkvAll[(size_t)(idx >> 6) * BIG + (size_t)token * 64 + (idx & 63)] =
        ((a0 + a1) + (a2 + a3)) * rs;
  }
}

// ================= attention: LDS-staged K/V tiles, double-buffered, phase-split softmax =================
__global__ __launch_bounds__(128) void attn_kernel(
    const float* qb, const float* __restrict__ kb,
    const float* __restrict__ vb, float* avb) {
  __shared__ float kv[2 * 2048];    // [buf][key*32 + (0..15 K | 16..31 V)], 16 KB
  int tid = threadIdx.x;
  int qt = 7 - (blockIdx.x & 7);    // heavy tiles dispatch first
  int h = blockIdx.y, b = blockIdx.z;
  int qi = qt * 128 + tid;
  size_t base = (size_t)b * SEQ * 64 + h * 16;
  float qv[16];
  {
    const float4* qr = (const float4*)(qb + base + (size_t)qi * 64);
#pragma unroll
    for (int c = 0; c < 4; ++c) {
      float4 t = qr[c];
      qv[4 * c] = t.x; qv[4 * c + 1] = t.y; qv[4 * c + 2] = t.z; qv[4 * c + 3] = t.w;
    }
  }
  int wavebase = __builtin_amdgcn_readfirstlane(qi);
  int myNT = (wavebase >> 6) + 1;   // tiles this wave computes
  int nt = 2 * qt + 2;              // tiles the block stages
  int kj = tid >> 1, part = tid & 1;
  const float* src0 = (part ? vb : kb) + base;
  float m = -1e30f, l = 0.f;
  float o[16];
#pragma unroll
  for (int d = 0; d < 16; ++d) o[d] = 0.f;
  float4 pA, pB, pC, pD;
  {  // prefetch tile 0
    const float4* s4 = (const float4*)(src0 + (size_t)kj * 64);
    pA = s4[0]; pB = s4[1]; pC = s4[2]; pD = s4[3];
  }
  for (int jt = 0; jt < nt; ++jt) {
    int buf = jt & 1;
    {  // write prefetched tile into LDS
      float4* d4 = (float4*)(&kv[buf * 2048 + tid * 16]);
      d4[0] = pA; d4[1] = pB; d4[2] = pC; d4[3] = pD;
    }
    __syncthreads();
    if (jt + 1 < nt) {  // prefetch next tile (in flight during compute)
      const float4* s4 = (const float4*)(src0 + (size_t)((jt + 1) * 64 + kj) * 64);
      pA = s4[0]; pB = s4[1]; pC = s4[2]; pD = s4[3];
    }
    if (jt < myNT) {
      const float* kvb = &kv[buf * 2048];
      bool diag = (jt == myNT - 1);
      for (int cc = 0; cc < 2; ++cc) {
        int cb = jt * 64 + cc * 32;
        float s[32];
#pragma unroll
        for (int u = 0; u < 32; ++u) {
          const float4* kr = (const float4*)(kvb + (cc * 32 + u) * 32);
          float4 k0 = kr[0], k1 = kr[1], k2 = kr[2], k3 = kr[3];
          float a0 = qv[0] * k0.x + qv[1] * k0.y + qv[2] * k0.z + qv[3] * k0.w;
          float a1 = qv[4] * k1.x + qv[5] * k1.y + qv[6] * k1.z + qv[7] * k1.w;
          float a2 = qv[8] * k2.x + qv[9] * k2.y + qv[10] * k2.z + qv[11] * k2.w;
          float a3 = qv[12] * k3.x + qv[13] * k3.y + qv[14] * k3.z + qv[15] * k3.w;
          s[u] = ((a0 + a1) + (a2 + a3)) * 0.25f;
        }
        if (diag) {
#pragma unroll
          for (int u = 0; u < 32; ++u) s[u] = (cb + u <= qi) ? s[u] : -1e30f;
        }
        float t0 = s[0], t1 = s[1], t2 = s[2], t3 = s[3];
#pragma unroll
        for (int u = 4; u < 32; u += 4) {
          t0 = fmaxf(t0, s[u]); t1 = fmaxf(t1, s[u + 1]);
          t2 = fmaxf(t2, s[u + 2]); t3 = fmaxf(t3, s[u + 3]);
        }
        float tm = fmaxf(fmaxf(t0, t1), fmaxf(t2, t3));
        float mn = fmaxf(m, tm);
        float cor = __expf(m - mn);
        m = mn;
        l *= cor;
#pragma unroll
        for (int d = 0; d < 16; ++d) o[d] *= cor;
        float l0 = 0, l1 = 0, l2 = 0, l3 = 0;
#pragma unroll
        for (int u = 0; u < 32; u += 4) {
          float p0 = __expf(s[u] - m);     s[u] = p0;     l0 += p0;
          float p1 = __expf(s[u + 1] - m); s[u + 1] = p1; l1 += p1;
          float p2 = __expf(s[u + 2] - m); s[u + 2] = p2; l2 += p2;
          float p3 = __expf(s[u + 3] - m); s[u + 3] = p3; l3 += p3;
        }
        l += (l0 + l1) + (l2 + l3);
#pragma unroll
        for (int u = 0; u < 32; ++u) {
          const float4* vr = (const float4*)(kvb + (cc * 32 + u) * 32 + 16);
          float4 v0 = vr[0], v1 = vr[1], v2 = vr[2], v3 = vr[3];
          float pu = s[u];
          o[0] = fmaf(pu, v0.x, o[0]);   o[1] = fmaf(pu, v0.y, o[1]);
          o[2] = fmaf(pu, v0.z, o[2]);   o[3] = fmaf(pu, v0.w, o[3]);
          o[4] = fmaf(pu, v1.x, o[4]);   o[5] = fmaf(pu, v1.y, o[5]);
          o[6] = fmaf(pu, v1.z, o[6]);   o[7] = fmaf(pu, v1.w, o[7]);
          o[8] = fmaf(pu, v2.x, o[8]);   o[9] = fmaf(pu, v2.y, o[9]);
          o[10] = fmaf(pu, v2.z, o[10]); o[11] = fmaf(pu, v2.w, o[11]);
          o[12] = fmaf(pu, v3.x, o[12]); o[13] = fmaf(pu, v3.y, o[13]);
          o[14] = fmaf(pu, v3.z, o[14]); o[15] = fmaf(pu, v3.w, o[15]);
        }
      }
    }
    __syncthreads();
  }
  float inv = 1.0f / l;
  float4* outp = (float4*)(avb + base + (size_t)qi * 64);
#pragma unroll
  for (int c = 0; c < 4; ++c) {
    float4 t;
    t.x = o[4 * c] * inv; t.y = o[4 * c + 1] * inv;
    t.z = o[4 * c + 2] * inv; t.w = o[4 * c + 3] * inv;
    outp[c] = t;
  }
}

// ================= womem_a: x1 = x + av @ wo^T (wo staged in LDS, 4 thr/token) =================
__global__ __launch_bounds__(256) void womem_a_kernel(
    const float* __restrict__ x, const float* avb,
    const float* __restrict__ wo, float* __restrict__ x1b) {
  __shared__ float wos[4096];   // 16 KB
  int tid = threadIdx.x;
  for (int i = tid; i < 4096; i += 256) wos[i] = wo[i];
  __syncthreads();
  int token = blockIdx.x * 64 + (tid & 63);
  int p = tid >> 6;
  float av[64];
  {
    const float4* a4 = (const float4*)(avb + (size_t)token * 64);
#pragma unroll
    for (int c = 0; c < 16; ++c) {
      float4 t = a4[c];
      av[4 * c] = t.x; av[4 * c + 1] = t.y; av[4 * c + 2] = t.z; av[4 * c + 3] = t.w;
    }
  }
  for (int o = 0; o < 16; ++o) {
    int r = p * 16 + o;
    const float4* wr = (const float4*)(wos + r * 64);
    float a0 = 0, a1 = 0, a2 = 0, a3 = 0;
#pragma unroll
    for (int c = 0; c < 16; ++c) {
      float4 w4 = wr[c];
      a0 = fmaf(av[4 * c], w4.x, a0);
      a1 = fmaf(av[4 * c + 1], w4.y, a1);
      a2 = fmaf(av[4 * c + 2], w4.z, a2);
      a3 = fmaf(av[4 * c + 3], w4.w, a3);
    }
    x1b[(size_t)token * 64 + r] = x[(size_t)token * 64 + r] + ((a0 + a1) + (a2 + a3));
  }
}

// ================= womem_b: memory-read stage (scores in LDS; weights in LDS) =================
__global__ __launch_bounds__(64) void womem_b_kernel(
    const float* __restrict__ x1b, const float* __restrict__ mqT,
    const float* __restrict__ addrNT, const float* __restrict__ mo,
    const float* __restrict__ mv, float* __restrict__ x2b) {
  __shared__ float mqs[2048];      // 8 KB
  __shared__ float ads[2048];      // 8 KB
  __shared__ float mos[4096];      // 16 KB
  __shared__ float scr[64 * 65];   // 16.6 KB  per-token 64 scores
  __shared__ float tval[64 * 9];
  __shared__ int   tidxs[64 * 9];
  int tid = threadIdx.x;
  for (int i = tid; i < 2048; i += 64) { mqs[i] = mqT[i]; ads[i] = addrNT[i]; }
  for (int i = tid; i < 4096; i += 64) mos[i] = mo[i];
  __syncthreads();
  int token = blockIdx.x * 64 + tid;
  int b = token >> 10;
  const float4* x14 = (const float4*)(x1b + (size_t)token * 64);
  // q = x1 @ mqT  (rmsnorm rs cancels in l2norm; mem_norm folded)
  float q[32];
#pragma unroll
  for (int a = 0; a < 32; ++a) q[a] = 0.f;
  for (int e4 = 0; e4 < 16; ++e4) {
    float4 xv = x14[e4];
    float tc[4] = {xv.x, xv.y, xv.z, xv.w};
#pragma unroll
    for (int ec = 0; ec < 4; ++ec) {
      float t = tc[ec];
      const float4* mq4 = (const float4*)(mqs + (e4 * 4 + ec) * 32);
#pragma unroll
      for (int a4 = 0; a4 < 8; ++a4) {
        float4 mm = mq4[a4];
        q[4 * a4]     = fmaf(t, mm.x, q[4 * a4]);
        q[4 * a4 + 1] = fmaf(t, mm.y, q[4 * a4 + 1]);
        q[4 * a4 + 2] = fmaf(t, mm.z, q[4 * a4 + 2]);
        q[4 * a4 + 3] = fmaf(t, mm.w, q[4 * a4 + 3]);
      }
    }
  }
  float qq = 0.f;
#pragma unroll
  for (int a = 0; a < 32; ++a) qq = fmaf(q[a], q[a], qq);
  float sinv = 4.0f / fmaxf(sqrtf(qq), 1e-12f);   // l2norm * (1/TEMP)
  // scores -> LDS
  for (int n4 = 0; n4 < 16; ++n4) {
    float a0 = 0, a1 = 0, a2 = 0, a3 = 0;
#pragma unroll
    for (int a = 0; a < 32; ++a) {
      float4 an = *(const float4*)(ads + a * 64 + n4 * 4);
      a0 = fmaf(q[a], an.x, a0);
      a1 = fmaf(q[a], an.y, a1);
      a2 = fmaf(q[a], an.z, a2);
      a3 = fmaf(q[a], an.w, a3);
    }
    scr[tid * 65 + n4 * 4]     = a0 * sinv;
    scr[tid * 65 + n4 * 4 + 1] = a1 * sinv;
    scr[tid * 65 + n4 * 4 + 2] = a2 * sinv;
    scr[tid * 65 + n4 * 4 + 3] = a3 * sinv;
  }
  // top-8 (strict > keeps lowest index on ties, matching lax.top_k)
  for (int kk = 0; kk < 8; ++kk) {
    float bv = -1e30f; int bi = 0;
    for (int n = 0; n < 64; ++n) {
      float v = scr[tid * 65 + n];
      if (v > bv) { bv = v; bi = n; }
    }
    tval[tid * 9 + kk] = bv;
    tidxs[tid * 9 + kk] = bi;
    scr[tid * 65 + bi] = -3e30f;
  }
  float vmax = tval[tid * 9];
  float psum = 0.f;
  for (int kk = 0; kk < 8; ++kk) {
    float pw = __expf(tval[tid * 9 + kk] - vmax);
    tval[tid * 9 + kk] = pw;
    psum += pw;
  }
  float isum = 1.0f / psum;
  float rv[64];
#pragma unroll
  for (int e = 0; e < 64; ++e) rv[e] = 0.f;
  for (int kk = 0; kk < 8; ++kk) {
    float wgt = tval[tid * 9 + kk] * isum;
    int ix = tidxs[tid * 9 + kk];
    const float4* mr = (const float4*)(mv + ((size_t)(b * 64 + ix)) * 64);
#pragma unroll
    for (int c = 0; c < 16; ++c) {
      float4 f = mr[c];
      rv[4 * c]     = fmaf(wgt, f.x, rv[4 * c]);
      rv[4 * c + 1] = fmaf(wgt, f.y, rv[4 * c + 1]);
      rv[4 * c + 2] = fmaf(wgt, f.z, rv[4 * c + 2]);
      rv[4 * c + 3] = fmaf(wgt, f.w, rv[4 * c + 3]);
    }
  }
  // x2 = x1 + rv @ mem_out^T
  float4* out4 = (float4*)(x2b + (size_t)token * 64);
  for (int e4 = 0; e4 < 16; ++e4) {
    float4 xv = x14[e4];
    float res[4];
#pragma unroll
    for (int ec = 0; ec < 4; ++ec) {
      const float4* mr = (const float4*)(mos + (e4 * 4 + ec) * 64);
      float a0 = 0, a1 = 0, a2 = 0, a3 = 0;
#pragma unroll
      for (int c = 0; c < 16; ++c) {
        float4 w4 = mr[c];
        a0 = fmaf(rv[4 * c], w4.x, a0);
        a1 = fmaf(rv[4 * c + 1], w4.y, a1);
        a2 = fmaf(rv[4 * c + 2], w4.z, a2);
        a3 = fmaf(rv[4 * c + 3], w4.w, a3);
      }
      res[ec] = ((a0 + a1) + (a2 + a3));
    }
    float4 t;
    t.x = xv.x + res[0]; t.y = xv.y + res[1];
    t.z = xv.z + res[2]; t.w = xv.w + res[3];
    out4[e4] = t;
  }
}

// ================= ffn1: hidT(bf16) = gelu(rmsnorm(x2)@w1c^T + b1), transposed store =================
__global__ __launch_bounds__(256) void ffn1_kernel(
    const float* __restrict__ x2b, const float* __restrict__ w1c,
    const float* __restrict__ b1, __hip_bfloat16* __restrict__ hidT) {
  __shared__ float w1s[128 * 64];   // 32 KB (half of w1)
  int tid = threadIdx.x;
  int chunk = blockIdx.y;
  for (int i = tid; i < 8192; i += 256) w1s[i] = w1c[chunk * 8192 + i];
  __syncthreads();
  int token = blockIdx.x * 64 + (tid & 63);
  int p = tid >> 6;
  const float4* x4 = (const float4*)(x2b + (size_t)token * 64);
  float xr[64];
#pragma unroll
  for (int c = 0; c < 16; ++c) {
    float4 t = x4[c];
    xr[4 * c] = t.x; xr[4 * c + 1] = t.y; xr[4 * c + 2] = t.z; xr[4 * c + 3] = t.w;
  }
  float s0 = 0, s1 = 0, s2 = 0, s3 = 0;
#pragma unroll
  for (int c = 0; c < 16; ++c) {
    s0 = fmaf(xr[4 * c], xr[4 * c], s0);
    s1 = fmaf(xr[4 * c + 1], xr[4 * c + 1], s1);
    s2 = fmaf(xr[4 * c + 2], xr[4 * c + 2], s2);
    s3 = fmaf(xr[4 * c + 3], xr[4 * c + 3], s3);
  }
  float rs = rsqrtf(((s0 + s1) + (s2 + s3)) * (1.0f / 64.0f) + 1e-5f);
  for (int o = 0; o < 32; ++o) {
    int rl = p * 32 + o;              // row within chunk
    int rg = chunk * 128 + rl;        // global hid row
    const float4* wr = (const float4*)(w1s + rl * 64);
    float a0 = 0, a1 = 0, a2 = 0, a3 = 0;
#pragma unroll
    for (int c = 0; c < 16; ++c) {
      float4 w4 = wr[c];
      a0 = fmaf(xr[4 * c], w4.x, a0);
      a1 = fmaf(xr[4 * c + 1], w4.y, a1);
      a2 = fmaf(xr[4 * c + 2], w4.z, a2);
      a3 = fmaf(xr[4 * c + 3], w4.w, a3);
    }
    float hv = ((a0 + a1) + (a2 + a3)) * rs + b1[rg];
    float g = 0.5f * hv * (1.0f + erff(hv * 0.70710678118654752f));
    hidT[(size_t)rg * NTOK + token] = __float2bfloat16(g);
  }
}

// ================= ffn2: out = x2 + hid @ w2^T + b2 (w2T staged in 2 LDS phases) =================
__global__ __launch_bounds__(256) void ffn2_kernel(
    const float* __restrict__ x2b, const __hip_bfloat16* __restrict__ hidT,
    const float* __restrict__ w2T, const float* __restrict__ b2,
    float* __restrict__ out) {
  __shared__ float w2s[128 * 64];   // 32 KB (half of w2T)
  __shared__ float acc[64 * 65];    // 16.6 KB
  int tid = threadIdx.x;
  int token = blockIdx.x * 64 + (tid & 63);
  int p = tid >> 6;
  int lrow = tid & 63;
  for (int i = tid; i < 64 * 65; i += 256) acc[i] = 0.f;
  float part[64];
#pragma unroll
  for (int e = 0; e < 64; ++e) part[e] = 0.f;
  for (int c = 0; c < 2; ++c) {
    __syncthreads();   // acc-init done / previous phase reads done
    for (int i = tid; i < 8192; i += 256) w2s[i] = w2T[c * 8192 + i];
    __syncthreads();
    for (int jo = 0; jo < 32; ++jo) {
      int jl = p * 32 + jo;
      int j = c * 128 + jl;
      float hv = __bfloat162float(hidT[(size_t)j * NTOK + token]);
      const float4* wr = (const float4*)(w2s + jl * 64);
#pragma unroll
      for (int cc = 0; cc < 16; ++cc) {
        float4 w4 = wr[cc];
        part[4 * cc]     = fmaf(hv, w4.x, part[4 * cc]);
        part[4 * cc + 1] = fmaf(hv, w4.y, part[4 * cc + 1]);
        part[4 * cc + 2] = fmaf(hv, w4.z, part[4 * cc + 2]);
        part[4 * cc + 3] = fmaf(hv, w4.w, part[4 * cc + 3]);
      }
    }
  }
  __syncthreads();
#pragma unroll
  for (int e = 0; e < 64; ++e) atomicAdd(&acc[lrow * 65 + e], part[e]);  // 2 lanes/bank: free
  __syncthreads();
  int e0 = p * 16;
#pragma unroll
  for (int i = 0; i < 16; ++i) {
    int e = e0 + i;
    out[(size_t)token * 64 + e] = x2b[(size_t)token * 64 + e] + b2[e] + acc[lrow * 65 + e];
  }
}

extern "C" void kernel_launch(void* const* d_in, const int* in_sizes, int n_in,
                              void* d_out, int out_size, void* d_ws, size_t ws_size,
                              hipStream_t stream) {
  const float* x    = (const float*)d_in[0];
  const float* addr = (const float*)d_in[1];
  const float* mv   = (const float*)d_in[2];
  const float* aw   = (const float*)d_in[3];
  const float* wq   = (const float*)d_in[4];
  const float* wk   = (const float*)d_in[5];
  const float* wv   = (const float*)d_in[6];
  const float* wo   = (const float*)d_in[7];
  const float* mw   = (const float*)d_in[8];
  const float* mq   = (const float*)d_in[9];
  const float* mo   = (const float*)d_in[10];
  const float* fw   = (const float*)d_in[11];
  const float* w1   = (const float*)d_in[12];
  const float* b1   = (const float*)d_in[13];
  const float* w2   = (const float*)d_in[14];
  const float* b2   = (const float*)d_in[15];

  float* ws = (float*)d_ws;
  const size_t BIG = (size_t)NTOK * 64;      // 2M floats
  float* qb  = ws;                // [0, 2M)
  float* kb  = ws + BIG;          // [2M, 4M)
  float* vb  = ws + 2 * BIG;      // [4M, 6M)
  float* avb = qb;                // attn writes over its own q slice
  float* x1b = kb;                // k dead after attn
  float* x2b = vb;                // v dead after attn
  __hip_bfloat16* hidT = (__hip_bfloat16*)d_ws;  // 16 MB over qb+kb (both dead by ffn1)
  float* sm = ws + 3 * BIG;
  float* wall   = sm;             // wqc|wkc|wvc  12288
  float* mqT    = sm + 12288;     // 2048
  float* addrNT = sm + 14336;     // 2048
  float* w1c    = sm + 16384;     // 16384
  float* w2T    = sm + 32768;     // 16384

  prep_kernel<<<64, 256, 0, stream>>>(addr, wq, wk, wv, aw, mw, mq, fw, w1, w2,
                                      wall, mqT, addrNT, w1c, w2T);
  qkv_kernel<<<512, 256, 0, stream>>>(x, wall, qb);
  attn_kernel<<<dim3(8, 4, BATCH), 128, 0, stream>>>(qb, kb, vb, avb);
  womem_a_kernel<<<512, 256, 0, stream>>>(x, avb, wo, x1b);
  womem_b_kernel<<<512, 64, 0, stream>>>(x1b, mqT, addrNT, mo, mv, x2b);
  ffn1_kernel<<<dim3(512, 2), 256, 0, stream>>>(x2b, w1c, b1, hidT);
  ffn2_kernel<<<512, 256, 0, stream>>>(x2b, hidT, w2T, b2, (float*)d_out);
}